// Round 1
// baseline (706.407 us; speedup 1.0000x reference)
//
#include <hip/hip_runtime.h>
#include <math.h>

// E2M1 (MXFP4) block weight quantizer, block=32, layer_max=6.0.
// Outputs concatenated in d_out (float32):
//   [0, N)        deq_weight          N = 8192*8192
//   [N, 2N)       encoded (0..15 as float)
//   [2N, 2N+B)    e8m0_scale + 127    B = N/32
//   [2N+B, 2N+2B) eps_base = 0.5*tanh(eps_param)
//
// R3: rocprof showed the timed region = poison-fill (~349us fixed) + kernel
// (~339us, 2.45 TB/s effective = 39% of achievable -> NOT BW-bound).
// This version attacks issue/latency overhead:
//  - 4 lanes per 32-block, 8 elems/lane: 2 independent 16B loads in flight,
//    half the waves, half the redundant per-block math (was 8x redundant).
//  - e8m0 = ceil(log2(a/6)) computed bit-exactly from float exponent/mantissa
//    (no v_log_f32, no ceilf). IEEE div a/6.0f kept so descale matches the
//    reference ulp-for-ulp; exponent extraction is then EXACT.
//  - tanh via v_exp_f32 + v_rcp_f32 (abs err ~1e-7, same accepted class).
//  - mantissa via packed nibble LUT 0xC8643210 = 2*{0,.5,1,1.5,2,3,4,6};
//    deq = ldexp(+-nib, e-1) (exact: tiny int * pow2).
//  - nontemporal load/store on the 3 big streams (no reuse).
//  - all index math 32-bit.

typedef float f32x4 __attribute__((ext_vector_type(4)));

constexpr unsigned long long NELEM = 8192ull * 8192ull;  // 67108864
constexpr unsigned           NBLK  = (unsigned)(NELEM / 32);  // 2097152

__global__ __launch_bounds__(256) void e2m1_quant_kernel(
    const float* __restrict__ w,
    const float* __restrict__ eps_p,
    float* __restrict__ out)
{
    const unsigned tid  = blockIdx.x * 256u + threadIdx.x;
    const unsigned b    = tid >> 2;        // block index [0, NBLK)
    const unsigned sub  = tid & 3u;        // lane-in-block (4 lanes/block)
    // lane covers elements [base, base+4) and [base+16, base+20):
    // every load/store instruction is fully contiguous across the wave.
    const unsigned base = b * 32u + sub * 4u;

    const f32x4* wp = reinterpret_cast<const f32x4*>(w + base);
    const f32x4 w0 = __builtin_nontemporal_load(wp);      // elems base..base+3
    const f32x4 w1 = __builtin_nontemporal_load(wp + 4);  // elems base+16..base+19
    const float p  = eps_p[b];                            // L1-broadcast to 4 lanes

    // ---- block amax: 8 local |.| maxes (abs folds into v_max modifiers),
    //      then butterfly across the aligned 4-lane group (2 shuffles).
    float a = fmaxf(fmaxf(fmaxf(fabsf(w0[0]), fabsf(w0[1])),
                          fmaxf(fabsf(w0[2]), fabsf(w0[3]))),
                    fmaxf(fmaxf(fabsf(w1[0]), fabsf(w1[1])),
                          fmaxf(fabsf(w1[2]), fabsf(w1[3]))));
    a = fmaxf(a, __shfl_xor(a, 1));
    a = fmaxf(a, __shfl_xor(a, 2));

    // ---- e8m0 = ceil(max(log2(a/6), -127)), bit-exact.
    // descale = a/6 via IEEE division: identical ulp to the reference.
    // For normal descale = m*2^(ex-127), m in [1,2):
    //   ceil(log2) = (ex-127) + (mantissa_bits != 0)
    // ex==0 covers descale==0 (log2=-inf -> -127) and denormals (< 2^-126,
    // clamp to -127; off-by-one only possible below 1e-37 -- unreachable here).
    const float descale = a / 6.0f;
    const unsigned du = __float_as_uint(descale);   // sign bit always 0
    const int ex = (int)(du >> 23);
    int e = ex - 127 + ((du & 0x7fffffu) ? 1 : 0);
    e = (ex == 0) ? -127 : e;
    e = (e < -127) ? -127 : e;
    const float rscale = ldexpf(1.0f, -e);          // exact 2^-e

    // ---- eps = 0.5*tanh(p) = 0.5*sign(p)*(1-e^-2|p|)/(1+e^-2|p|)
    const float t  = fabsf(p);
    const float em = __expf(-2.0f * t);             // v_exp_f32 path
    const float th = (1.0f - em) * __builtin_amdgcn_rcpf(1.0f + em);
    const float ep = 0.5f * copysignf(th, p);

    const float vals[8] = {w0[0], w0[1], w0[2], w0[3],
                           w1[0], w1[1], w1[2], w1[3]};
    float dq[8], ec[8];

#pragma unroll
    for (int i = 0; i < 8; ++i) {
        const float wn = vals[i] * rscale;          // exact pow2 mul
        const float as = fmaxf(fabsf(wn) + ep, 0.0f);
        // threshold-count encode against E2M1 bounds (exact fp32 compares,
        // same semantics as the reference's sum of (as > bounds))
        const int o = (as > 0.25f) + (as > 0.75f) + (as > 1.25f) + (as > 1.75f)
                    + (as > 2.5f)  + (as > 3.5f)  + (as > 5.0f);
        // sign(w_norm)=+1 -> 0; zero or negative -> 1 (floor((2-sign)/2))
        const bool neg = (wn <= 0.0f);
        // 2*E2M1_VALUES[o] = {0,1,2,3,4,6,8,12} packed as nibbles
        const int nib = (int)((0xC8643210u >> (o * 4)) & 0xFu);
        dq[i] = ldexpf((float)(neg ? -nib : nib), e - 1);  // exact
        ec[i] = (float)(o | (neg ? 8 : 0));
    }

    // ---- stores: each instruction covers a contiguous 64B-aligned span/wave
    f32x4* dptr = reinterpret_cast<f32x4*>(out + base);
    __builtin_nontemporal_store((f32x4){dq[0], dq[1], dq[2], dq[3]}, dptr);
    __builtin_nontemporal_store((f32x4){dq[4], dq[5], dq[6], dq[7]}, dptr + 4);
    f32x4* eptr = reinterpret_cast<f32x4*>(out + NELEM + base);
    __builtin_nontemporal_store((f32x4){ec[0], ec[1], ec[2], ec[3]}, eptr);
    __builtin_nontemporal_store((f32x4){ec[4], ec[5], ec[6], ec[7]}, eptr + 4);

    if (sub == 0) {
        // 16 lanes/wave -> two contiguous 64B dword stores per wave
        out[2 * NELEM + b]        = (float)(e + 127);  // e8m0_scale_uint8
        out[2 * NELEM + NBLK + b] = ep;                // eps_base
    }
}

extern "C" void kernel_launch(void* const* d_in, const int* in_sizes, int n_in,
                              void* d_out, int out_size, void* d_ws, size_t ws_size,
                              hipStream_t stream) {
    const float* w     = (const float*)d_in[0];   // weight_fp  [8192*8192]
    const float* eps_p = (const float*)d_in[1];   // eps_param  [2097152]
    float* out = (float*)d_out;

    const unsigned n_threads = NBLK * 4u;         // 8,388,608
    const int block = 256;
    const int grid  = (int)(n_threads / (unsigned)block);  // 32,768
    e2m1_quant_kernel<<<grid, block, 0, stream>>>(w, eps_p, out);
}